// Round 8
// baseline (223.547 us; speedup 1.0000x reference)
//
#include <hip/hip_runtime.h>
#include <hip/hip_bf16.h>
#include <math.h>

// Problem constants (CPUEfficientCausalAttention): B=2, S=2048, HIDDEN=1024, H=16, hd=64
#define HIDDEN 1024
#define HEADS 16
#define HDIM 64
#define BATCH 2
#define SEQ 2048
#define BHN (BATCH*HEADS)   // 32
#define MTOT (BATCH*SEQ)    // 4096

typedef __attribute__((ext_vector_type(8))) short short8;   // 8 bf16 (16x16x32 A/B frag)
typedef __attribute__((ext_vector_type(4))) short short4v;  // 4 bf16 (16x16x16 A/B frag)
typedef __attribute__((ext_vector_type(4))) float floatx4;  // MFMA C/D frag

// global -> LDS direct (16B per lane; LDS dst is wave-uniform base, +lane*16 implicit)
#define GL2LDS(gsrc, ldst) __builtin_amdgcn_global_load_lds( \
    (const __attribute__((address_space(1))) void*)(gsrc), \
    (__attribute__((address_space(3))) void*)(ldst), 16, 0, 0)

__device__ __forceinline__ short f2bf(float f) {
  union { float f; unsigned u; } v; v.f = f;
  unsigned u = v.u;
  unsigned r = (u + 0x7fffu + ((u >> 16) & 1u)) >> 16;  // RNE
  return (short)r;
}

// One fused fp32->bf16 cast for x (1048576 vec4), qkv_w (786432), out_w (262144)
__global__ __launch_bounds__(256) void cvt3_f32_bf16(
    const float* __restrict__ a, const float* __restrict__ b, const float* __restrict__ c,
    short* __restrict__ oa, short* __restrict__ ob, short* __restrict__ oc) {
  int i = blockIdx.x * 256 + threadIdx.x;
  const float* src; short* dst; int j;
  if (i < 1048576)      { src = a; dst = oa; j = i; }
  else if (i < 1835008) { src = b; dst = ob; j = i - 1048576; }
  else                  { src = c; dst = oc; j = i - 1835008; }
  float4 f = reinterpret_cast<const float4*>(src)[j];
  short4 o;
  o.x = f2bf(f.x); o.y = f2bf(f.y); o.z = f2bf(f.z); o.w = f2bf(f.w);
  reinterpret_cast<short4*>(dst)[j] = o;
}

// C[M,N] = A[M,K] @ B[N,K]^T, bf16 in, fp32 accum.  (round-7 structure, unchanged)
// 128xBN tile, BK=64 (XOR-swizzled LDS rows of 128B keep b128 reads bank-minimal),
// 4 waves in 2x2, each wave 64x(BN/2). Hoisted staging pointers + T1 XCD swizzle.
// EPI==1 (BN=128): scatter qkv epilogue (q scaled by hd^-0.5*log2e, k row-major, v transposed)
// EPI==2: plain fp32 C row-major
template<int EPI, int BN>
__global__ __launch_bounds__(256) void gemm_bt(
    const short* __restrict__ A, const short* __restrict__ B,
    int M, int N, int K,
    float* __restrict__ outF,
    short* __restrict__ outQ, short* __restrict__ outK, short* __restrict__ outV)
{
  constexpr int WN = BN / 2;    // wave col extent
  constexpr int NI = BN / 32;   // 16-col tiles per wave
  constexpr int BRD = BN / 32;  // B staging loads per thread
  __shared__ __align__(16) short As[128*64];
  __shared__ __align__(16) short Bs[BN*64];
  const int tid = threadIdx.x;
  const int wv = tid >> 6;
  const int lane = tid & 63;
  const int l15 = lane & 15;
  const int quad = lane >> 4;
  const int swl = l15 & 7;
  const int wm = wv >> 1, wn = wv & 1;

  // T1 XCD swizzle (bijective since nwg % 8 == 0)
  const int nwg = gridDim.x * gridDim.y;
  const int cpx = nwg >> 3;
  int wg = (int)blockIdx.y * gridDim.x + blockIdx.x;
  wg = (wg & 7) * cpx + (wg >> 3);
  const int bx = wg % gridDim.x, by = wg / gridDim.x;
  const int row0 = by * 128, col0 = bx * BN;

  const int nsteps = K >> 6;

  // hoisted per-lane staging source pointers (advance by 64 shorts per K-step)
  const short* aSrc[4];
#pragma unroll
  for (int rd = 0; rd < 4; ++rd) {
    int chunk = rd * 256 + tid;
    int r = chunk >> 3, c = ((chunk & 7) ^ (r & 7)) << 3;
    aSrc[rd] = A + (long)(row0 + r) * K + c;
  }
  const short* bSrc[BRD];
#pragma unroll
  for (int rd = 0; rd < BRD; ++rd) {
    int chunk = rd * 256 + tid;
    int r = chunk >> 3, c = ((chunk & 7) ^ (r & 7)) << 3;
    bSrc[rd] = B + (long)(col0 + r) * K + c;
  }

  floatx4 acc[4][NI];
#pragma unroll
  for (int i = 0; i < 4; i++)
#pragma unroll
    for (int j = 0; j < NI; j++) acc[i][j] = (floatx4){0.f, 0.f, 0.f, 0.f};

  for (int t = 0; t < nsteps; ++t) {
    // stage A [128][64] and B [BN][64], XOR-swizzled on source col
#pragma unroll
    for (int rd = 0; rd < 4; ++rd) {
      GL2LDS(aSrc[rd], As + (rd * 256 + wv * 64) * 8);
      aSrc[rd] += 64;
    }
#pragma unroll
    for (int rd = 0; rd < BRD; ++rd) {
      GL2LDS(bSrc[rd], Bs + (rd * 256 + wv * 64) * 8);
      bSrc[rd] += 64;
    }
    __syncthreads();

    short8 af[4][2], bfr[NI][2];
#pragma unroll
    for (int mi = 0; mi < 4; mi++) {
      const short* ap = As + (wm * 64 + mi * 16 + l15) * 64;
#pragma unroll
      for (int kk = 0; kk < 2; kk++)
        af[mi][kk] = *(const short8*)(ap + (((kk * 4 + quad) ^ swl) << 3));
    }
#pragma unroll
    for (int ni = 0; ni < NI; ni++) {
      const short* bp = Bs + (wn * WN + ni * 16 + l15) * 64;
#pragma unroll
      for (int kk = 0; kk < 2; kk++)
        bfr[ni][kk] = *(const short8*)(bp + (((kk * 4 + quad) ^ swl) << 3));
    }
    __builtin_amdgcn_s_setprio(1);
#pragma unroll
    for (int mi = 0; mi < 4; mi++)
#pragma unroll
      for (int ni = 0; ni < NI; ni++)
#pragma unroll
        for (int kk = 0; kk < 2; kk++)
          acc[mi][ni] = __builtin_amdgcn_mfma_f32_16x16x32_bf16(af[mi][kk], bfr[ni][kk], acc[mi][ni], 0, 0, 0);
    __builtin_amdgcn_s_setprio(0);
    __syncthreads();
  }

  if (EPI == 2) {
#pragma unroll
    for (int mi = 0; mi < 4; mi++) {
      int rr = row0 + wm * 64 + mi * 16 + quad * 4;
#pragma unroll
      for (int ni = 0; ni < NI; ni++) {
        int cc = col0 + wn * WN + ni * 16 + l15;
#pragma unroll
        for (int r = 0; r < 4; r++)
          outF[(long)(rr + r) * N + cc] = acc[mi][ni][r];
      }
    }
  } else {
    // qkv scatter: j = t*1024 + h*64 + d ; i = b*2048 + s
#pragma unroll
    for (int mi = 0; mi < 4; mi++) {
      int rowg = row0 + wm * 64 + mi * 16 + quad * 4;
#pragma unroll
      for (int ni = 0; ni < NI; ni++) {
        int j = col0 + wn * WN + ni * 16 + l15;
        int t = j >> 10;
        int rem = j & 1023;
        int h = rem >> 6, d = rem & 63;
#pragma unroll
        for (int r = 0; r < 4; r++) {
          int i = rowg + r;
          int b = i >> 11, s = i & 2047;
          int bh = b * HEADS + h;
          float v = acc[mi][ni][r];
          // q scale = hd^-0.5 * log2(e) so flash can use raw v_exp_f32 (2^x)
          if (t == 0)      outQ[(bh * SEQ + s) * HDIM + d] = f2bf(v * 0.18033688011112042f);
          else if (t == 1) outK[(bh * SEQ + s) * HDIM + d] = f2bf(v);
          else             outV[(bh * HDIM + d) * SEQ + s] = f2bf(v);          // transposed
        }
      }
    }
  }
}

// Flash attention v11: direct-L2 operands, BARRIER-FREE main loop.
//  - K/V per XCD: default dispatch puts head h on XCD h%8 (grid.x=bh, 32%8==0) ->
//    4 heads x 512KB = 2MB, L2-resident (FETCH=12.3MB == compulsory confirms). So
//    LDS staging + per-tile __syncthreads (vmcnt-0 drain, 4-wave lockstep) was pure
//    overhead (guide lesson #7 / m169: dropping staging at L2-fit S=1024 = +26%).
//  - operand frags load straight from global (addressing == unswizzled v10 LDS reads;
//    K-frag pattern is identical in shape to the proven direct Q load):
//      K A-frag: kg[(bh*S + kt*64 + kh*32+sub*16+l15)*64 + quad*8 (+32)]   (16B)
//      V B-frag: vT[(bh*64 + nt*16+l15)*S + kt*64 + kh*32+sub*16+quad*4]   (8B)
//  - waves run with ZERO synchronization until the final merge; loads issued up-front
//    per tile, compiler pipelines with counted vmcnt across the MFMA/softmax phases.
//  - 2x2 (q-half x kpos-half) split kept: halves per-wave L2 read volume; additive
//    static-max partials merged via conflict-free field-major LDS scratch (20KB).
__global__ __launch_bounds__(256, 4) void flash_attn(
    const short* __restrict__ qg, const short* __restrict__ kg,
    const short* __restrict__ vT, short* __restrict__ attn)
{
  __shared__ float redO[32 * 128];   // merge scratch [field][thr], 16 KB
  __shared__ float redL[8 * 128];    //                             4 KB

  const int tid = threadIdx.x;
  const int wv = tid >> 6, lane = tid & 63;
  const int l15 = lane & 15, quad = lane >> 4;
  const int bh = blockIdx.x;
  // balanced work mapping (bijective on 0..31): sgrp 0..3 -> {y0, 15-y0, 16+y0, 31-y0}
  const int yl = (int)blockIdx.y;
  const int sgrp = yl >> 3, y0 = yl & 7;
  const int yp = ((sgrp >> 1) << 4) + ((sgrp & 1) ? (15 - y0) : y0);
  const int rt = 31 - yp;                   // q row-tile (64 rows); ntiles = rt+1
  const int qh = wv >> 1;                   // q-half: 32 rows
  const int kh = wv & 1;                    // kpos-half: 32 positions per tile
  const int m0 = rt * 64 + qh * 32;         // wave's first q row

  // Q frags (persistent): B-operand for S^T: n=q=m0+g*16+l15, k=d=kk*32+quad*8+j
  short8 aq[2][2];
#pragma unroll
  for (int g = 0; g < 2; g++) {
    const short* qp = qg + (long)(bh * SEQ + m0 + g * 16 + l15) * HDIM + quad * 8;
    aq[g][0] = *(const short8*)qp;
    aq[g][1] = *(const short8*)(qp + 32);
  }

  // direct-L2 operand pointers (advance per tile; sub-offsets folded as immediates)
  const short* kp[2];                       // K rows kh*32 + sub*16 + l15, col quad*8
#pragma unroll
  for (int sub = 0; sub < 2; sub++)
    kp[sub] = kg + ((long)bh * SEQ + kh * 32 + sub * 16 + l15) * HDIM + quad * 8;
  const short* vp[4];                       // V^T rows d = nt*16 + l15, col kh*32 + quad*4
#pragma unroll
  for (int nt = 0; nt < 4; nt++)
    vp[nt] = vT + ((long)bh * HDIM + nt * 16 + l15) * SEQ + kh * 32 + quad * 4;

  const short ONE = (short)0x3F80;  // bf16 1.0
  const short4v ones4 = {ONE, ONE, ONE, ONE};

  floatx4 o[2][4], lsum[2];
#pragma unroll
  for (int g = 0; g < 2; g++) {
    lsum[g] = (floatx4){0.f, 0.f, 0.f, 0.f};
#pragma unroll
    for (int nt = 0; nt < 4; nt++) o[g][nt] = (floatx4){0.f, 0.f, 0.f, 0.f};
  }

  const int ntiles = rt + 1;

  for (int kt = 0; kt < ntiles; ++kt) {
    // ---- issue ALL of this tile's loads up-front (K 4x16B, V 8x8B) ----
    short8 kf[2][2];
#pragma unroll
    for (int sub = 0; sub < 2; sub++) {
      kf[sub][0] = *(const short8*)(kp[sub]);        // k = d 0..31
      kf[sub][1] = *(const short8*)(kp[sub] + 32);   // k = d 32..63
      kp[sub] += 64 * HDIM;
    }
    short4v bv[2][4];
#pragma unroll
    for (int nt = 0; nt < 4; nt++) {
#pragma unroll
      for (int sub = 0; sub < 2; sub++)
        bv[sub][nt] = *(const short4v*)(vp[nt] + sub * 16);
      vp[nt] += 64;
    }

    // ---- S^T quarter = K[kh-half] . Q[qh-half]^T (16x16x32) ----
    // D[row=kpos(quad*4+r) within sub][col=q(l15)]
    floatx4 sc[2][2];                        // [g][sub]
#pragma unroll
    for (int g = 0; g < 2; g++)
#pragma unroll
      for (int sub = 0; sub < 2; sub++) sc[g][sub] = (floatx4){0.f, 0.f, 0.f, 0.f};
    __builtin_amdgcn_s_setprio(1);
#pragma unroll
    for (int sub = 0; sub < 2; sub++)
#pragma unroll
      for (int g = 0; g < 2; g++) {
        sc[g][sub] = __builtin_amdgcn_mfma_f32_16x16x32_bf16(kf[sub][0], aq[g][0], sc[g][sub], 0, 0, 0);
        sc[g][sub] = __builtin_amdgcn_mfma_f32_16x16x32_bf16(kf[sub][1], aq[g][1], sc[g][sub], 0, 0, 0);
      }
    __builtin_amdgcn_s_setprio(0);

    // ---- softmax (static max, exp2 domain) + pack P into K=16 A-frags (registers) ----
    short4v pa[2][2];
#pragma unroll
    for (int g = 0; g < 2; g++) {
      const int qrow = m0 + g * 16 + l15;
#pragma unroll
      for (int sub = 0; sub < 2; sub++) {
        const int kbase = kt * 64 + kh * 32 + sub * 16;
        const bool full = (kbase + 15) <= (m0 + g * 16);  // wave-uniform per (g,sub)
        unsigned u[4];
#pragma unroll
        for (int r = 0; r < 4; r++) {
          float pe = __builtin_amdgcn_exp2f(sc[g][sub][r]);
          if (!full) {
            const int kpos = kbase + quad * 4 + r;
            pe = (kpos <= qrow) ? pe : 0.f;
          }
          u[r] = __builtin_bit_cast(unsigned, pe);
        }
        uint2 w;
        // bf16-pair pack: select hi bytes of (u[r], u[r+1]) -> implicit trunc to bf16
        w.x = __builtin_amdgcn_perm(u[1], u[0], 0x07060302);   // k = quad*4 + {0,1}
        w.y = __builtin_amdgcn_perm(u[3], u[2], 0x07060302);   // k = quad*4 + {2,3}
        pa[g][sub] = __builtin_bit_cast(short4v, w);
      }
    }

    // ---- partial P @ V and P @ ones via 16x16x16 MFMA (k-dim = wave's kpos-half) ----
    __builtin_amdgcn_s_setprio(1);
#pragma unroll
    for (int sub = 0; sub < 2; sub++)
#pragma unroll
      for (int g = 0; g < 2; g++) {
        lsum[g] = __builtin_amdgcn_mfma_f32_16x16x16bf16_1k(pa[g][sub], ones4, lsum[g], 0, 0, 0);
#pragma unroll
        for (int nt = 0; nt < 4; nt++)
          o[g][nt] = __builtin_amdgcn_mfma_f32_16x16x16bf16_1k(pa[g][sub], bv[sub][nt], o[g][nt], 0, 0, 0);
      }
    __builtin_amdgcn_s_setprio(0);
  }

  // ---- merge kpos-half partials: kh=1 writes to LDS scratch, kh=0 adds ----
  // FIELD-MAJOR layout [field][thr]: thr = qh*64+lane is contiguous -> conflict-free.
  __syncthreads();
  const int thr = qh * 64 + lane;
  if (kh == 1) {
#pragma unroll
    for (int g = 0; g < 2; g++) {
#pragma unroll
      for (int nt = 0; nt < 4; nt++)
#pragma unroll
        for (int r = 0; r < 4; r++)
          redO[(g * 16 + nt * 4 + r) * 128 + thr] = o[g][nt][r];
#pragma unroll
      for (int r = 0; r < 4; r++) redL[(g * 4 + r) * 128 + thr] = lsum[g][r];
    }
  }
  __syncthreads();
  if (kh == 0) {
    const int b = bh >> 4, h = bh & 15;
#pragma unroll
    for (int g = 0; g < 2; g++) {
      floatx4 lt = lsum[g];
#pragma unroll
      for (int r = 0; r < 4; r++) lt[r] += redL[(g * 4 + r) * 128 + thr];
#pragma unroll
      for (int r = 0; r < 4; r++) {
        const float inv = 1.0f / lt[r];
        const int srow = m0 + g * 16 + quad * 4 + r;
#pragma unroll
        for (int nt = 0; nt < 4; nt++) {
          float val = o[g][nt][r] + redO[(g * 16 + nt * 4 + r) * 128 + thr];
          attn[(long)(b * SEQ + srow) * HIDDEN + h * HDIM + nt * 16 + l15] = f2bf(val * inv);
        }
      }
    }
  }
}

extern "C" void kernel_launch(void* const* d_in, const int* in_sizes, int n_in,
                              void* d_out, int out_size, void* d_ws, size_t ws_size,
                              hipStream_t stream) {
  const float* x     = (const float*)d_in[0];  // [2,2048,1024]
  const float* qkv_w = (const float*)d_in[1];  // [3072,1024]
  const float* out_w = (const float*)d_in[2];  // [1024,1024]
  float* out = (float*)d_out;                  // [2,2048,1024] fp32

  short* xb   = (short*)d_ws;                       // 4096*1024
  short* wqb  = xb  + MTOT * HIDDEN;                // 3072*1024
  short* wob  = wqb + 3 * HIDDEN * HIDDEN;          // 1024*1024
  short* qB   = wob + HIDDEN * HIDDEN;              // 32*2048*64
  short* kB   = qB  + BHN * SEQ * HDIM;
  short* vTB  = kB  + BHN * SEQ * HDIM;
  short* attn = vTB + BHN * SEQ * HDIM;             // 4096*1024

  // fused bf16 casts: (4096+3072+1024)*1024/4 = 2097152 vec4 -> 8192 blocks
  cvt3_f32_bf16<<<dim3(8192), dim3(256), 0, stream>>>(x, qkv_w, out_w, xb, wqb, wob);

  // QKV projection: M=4096, N=3072, K=1024, BK=64 (proven 128x128 structure + hoist + T1)
  gemm_bt<1, 128><<<dim3(3 * HIDDEN / 128, MTOT / 128), dim3(256), 0, stream>>>(
      xb, wqb, MTOT, 3 * HIDDEN, HIDDEN, nullptr, qB, kB, vTB);

  // causal attention: 64-row blocks, 2x2 (q-half x kpos-half) wave split, v11 direct-L2
  flash_attn<<<dim3(BHN, SEQ / 64), dim3(256), 0, stream>>>(qB, kB, vTB, attn);

  // output projection: M=4096, N=1024, K=1024 (128x64 tiles -> 512 blocks), BK=64
  gemm_bt<2, 64><<<dim3(HIDDEN / 64, MTOT / 128), dim3(256), 0, stream>>>(
      attn, wob, MTOT, HIDDEN, HIDDEN, out, nullptr, nullptr, nullptr);
}

// Round 9
// 170.169 us; speedup vs baseline: 1.3137x; 1.3137x over previous
//
#include <hip/hip_runtime.h>
#include <hip/hip_bf16.h>
#include <math.h>

// Problem constants (CPUEfficientCausalAttention): B=2, S=2048, HIDDEN=1024, H=16, hd=64
#define HIDDEN 1024
#define HEADS 16
#define HDIM 64
#define BATCH 2
#define SEQ 2048
#define BHN (BATCH*HEADS)   // 32
#define MTOT (BATCH*SEQ)    // 4096

typedef __attribute__((ext_vector_type(8))) short short8;   // 8 bf16 (16x16x32 A/B frag)
typedef __attribute__((ext_vector_type(4))) short short4v;  // 4 bf16 (16x16x16 A/B frag)
typedef __attribute__((ext_vector_type(4))) float floatx4;  // MFMA C/D frag

// global -> LDS direct (16B per lane; LDS dst is wave-uniform base, +lane*16 implicit)
#define GL2LDS(gsrc, ldst) __builtin_amdgcn_global_load_lds( \
    (const __attribute__((address_space(1))) void*)(gsrc), \
    (__attribute__((address_space(3))) void*)(ldst), 16, 0, 0)

__device__ __forceinline__ short f2bf(float f) {
  union { float f; unsigned u; } v; v.f = f;
  unsigned u = v.u;
  unsigned r = (u + 0x7fffu + ((u >> 16) & 1u)) >> 16;  // RNE
  return (short)r;
}

// One fused fp32->bf16 cast for x (1048576 vec4), qkv_w (786432), out_w (262144)
__global__ __launch_bounds__(256) void cvt3_f32_bf16(
    const float* __restrict__ a, const float* __restrict__ b, const float* __restrict__ c,
    short* __restrict__ oa, short* __restrict__ ob, short* __restrict__ oc) {
  int i = blockIdx.x * 256 + threadIdx.x;
  const float* src; short* dst; int j;
  if (i < 1048576)      { src = a; dst = oa; j = i; }
  else if (i < 1835008) { src = b; dst = ob; j = i - 1048576; }
  else                  { src = c; dst = oc; j = i - 1835008; }
  float4 f = reinterpret_cast<const float4*>(src)[j];
  short4 o;
  o.x = f2bf(f.x); o.y = f2bf(f.y); o.z = f2bf(f.z); o.w = f2bf(f.w);
  reinterpret_cast<short4*>(dst)[j] = o;
}

// C[M,N] = A[M,K] @ B[N,K]^T, bf16 in, fp32 accum.  (round-7 structure, unchanged)
// 128xBN tile, BK=64 (XOR-swizzled LDS rows of 128B keep b128 reads bank-minimal),
// 4 waves in 2x2, each wave 64x(BN/2). Hoisted staging pointers + T1 XCD swizzle.
// EPI==1 (BN=128): scatter qkv epilogue (q scaled by hd^-0.5*log2e, k row-major, v transposed)
// EPI==2: plain fp32 C row-major
template<int EPI, int BN>
__global__ __launch_bounds__(256) void gemm_bt(
    const short* __restrict__ A, const short* __restrict__ B,
    int M, int N, int K,
    float* __restrict__ outF,
    short* __restrict__ outQ, short* __restrict__ outK, short* __restrict__ outV)
{
  constexpr int WN = BN / 2;    // wave col extent
  constexpr int NI = BN / 32;   // 16-col tiles per wave
  constexpr int BRD = BN / 32;  // B staging loads per thread
  __shared__ __align__(16) short As[128*64];
  __shared__ __align__(16) short Bs[BN*64];
  const int tid = threadIdx.x;
  const int wv = tid >> 6;
  const int lane = tid & 63;
  const int l15 = lane & 15;
  const int quad = lane >> 4;
  const int swl = l15 & 7;
  const int wm = wv >> 1, wn = wv & 1;

  // T1 XCD swizzle (bijective since nwg % 8 == 0)
  const int nwg = gridDim.x * gridDim.y;
  const int cpx = nwg >> 3;
  int wg = (int)blockIdx.y * gridDim.x + blockIdx.x;
  wg = (wg & 7) * cpx + (wg >> 3);
  const int bx = wg % gridDim.x, by = wg / gridDim.x;
  const int row0 = by * 128, col0 = bx * BN;

  const int nsteps = K >> 6;

  // hoisted per-lane staging source pointers (advance by 64 shorts per K-step)
  const short* aSrc[4];
#pragma unroll
  for (int rd = 0; rd < 4; ++rd) {
    int chunk = rd * 256 + tid;
    int r = chunk >> 3, c = ((chunk & 7) ^ (r & 7)) << 3;
    aSrc[rd] = A + (long)(row0 + r) * K + c;
  }
  const short* bSrc[BRD];
#pragma unroll
  for (int rd = 0; rd < BRD; ++rd) {
    int chunk = rd * 256 + tid;
    int r = chunk >> 3, c = ((chunk & 7) ^ (r & 7)) << 3;
    bSrc[rd] = B + (long)(col0 + r) * K + c;
  }

  floatx4 acc[4][NI];
#pragma unroll
  for (int i = 0; i < 4; i++)
#pragma unroll
    for (int j = 0; j < NI; j++) acc[i][j] = (floatx4){0.f, 0.f, 0.f, 0.f};

  for (int t = 0; t < nsteps; ++t) {
    // stage A [128][64] and B [BN][64], XOR-swizzled on source col
#pragma unroll
    for (int rd = 0; rd < 4; ++rd) {
      GL2LDS(aSrc[rd], As + (rd * 256 + wv * 64) * 8);
      aSrc[rd] += 64;
    }
#pragma unroll
    for (int rd = 0; rd < BRD; ++rd) {
      GL2LDS(bSrc[rd], Bs + (rd * 256 + wv * 64) * 8);
      bSrc[rd] += 64;
    }
    __syncthreads();

    short8 af[4][2], bfr[NI][2];
#pragma unroll
    for (int mi = 0; mi < 4; mi++) {
      const short* ap = As + (wm * 64 + mi * 16 + l15) * 64;
#pragma unroll
      for (int kk = 0; kk < 2; kk++)
        af[mi][kk] = *(const short8*)(ap + (((kk * 4 + quad) ^ swl) << 3));
    }
#pragma unroll
    for (int ni = 0; ni < NI; ni++) {
      const short* bp = Bs + (wn * WN + ni * 16 + l15) * 64;
#pragma unroll
      for (int kk = 0; kk < 2; kk++)
        bfr[ni][kk] = *(const short8*)(bp + (((kk * 4 + quad) ^ swl) << 3));
    }
    __builtin_amdgcn_s_setprio(1);
#pragma unroll
    for (int mi = 0; mi < 4; mi++)
#pragma unroll
      for (int ni = 0; ni < NI; ni++)
#pragma unroll
        for (int kk = 0; kk < 2; kk++)
          acc[mi][ni] = __builtin_amdgcn_mfma_f32_16x16x32_bf16(af[mi][kk], bfr[ni][kk], acc[mi][ni], 0, 0, 0);
    __builtin_amdgcn_s_setprio(0);
    __syncthreads();
  }

  if (EPI == 2) {
#pragma unroll
    for (int mi = 0; mi < 4; mi++) {
      int rr = row0 + wm * 64 + mi * 16 + quad * 4;
#pragma unroll
      for (int ni = 0; ni < NI; ni++) {
        int cc = col0 + wn * WN + ni * 16 + l15;
#pragma unroll
        for (int r = 0; r < 4; r++)
          outF[(long)(rr + r) * N + cc] = acc[mi][ni][r];
      }
    }
  } else {
    // qkv scatter: j = t*1024 + h*64 + d ; i = b*2048 + s
#pragma unroll
    for (int mi = 0; mi < 4; mi++) {
      int rowg = row0 + wm * 64 + mi * 16 + quad * 4;
#pragma unroll
      for (int ni = 0; ni < NI; ni++) {
        int j = col0 + wn * WN + ni * 16 + l15;
        int t = j >> 10;
        int rem = j & 1023;
        int h = rem >> 6, d = rem & 63;
#pragma unroll
        for (int r = 0; r < 4; r++) {
          int i = rowg + r;
          int b = i >> 11, s = i & 2047;
          int bh = b * HEADS + h;
          float v = acc[mi][ni][r];
          // q scale = hd^-0.5 * log2(e) so flash can use raw v_exp_f32 (2^x)
          if (t == 0)      outQ[(bh * SEQ + s) * HDIM + d] = f2bf(v * 0.18033688011112042f);
          else if (t == 1) outK[(bh * SEQ + s) * HDIM + d] = f2bf(v);
          else             outV[(bh * HDIM + d) * SEQ + s] = f2bf(v);          // transposed
        }
      }
    }
  }
}

// Flash attention v10 (PROVEN, round-7): v9 structure (2x2 q-half x kpos-half wave
// split, additive static-max partials, LDS merge) + three issue-rate fixes:
//  1. merge scratch FIELD-MAJOR [field][thr] -> conflict-free.
//  2. staging source pointers hoisted (computed once, advanced per tile).
//  3. P-pack via v_perm_b32 (1 inst/pair, implicit bf16 trunc).
// NOTE (round-8 lesson): the GL2LDS->LDS->next-barrier pipeline IS the latency hider
// (prefetch distance 1: barrier drains loads one full compute-phase old). Replacing
// it with direct per-tile L2 loads exposed ~200cyc/tile -> 2.3x regression. Keep.
__global__ __launch_bounds__(256, 4) void flash_attn(
    const short* __restrict__ qg, const short* __restrict__ kg,
    const short* __restrict__ vT, short* __restrict__ attn)
{
  __shared__ __align__(16) short Ks[2][64 * 64];
  __shared__ __align__(16) short Vs[2][64 * 64];

  const int tid = threadIdx.x;
  const int wv = tid >> 6, lane = tid & 63;
  const int l15 = lane & 15, quad = lane >> 4;
  const int bh = blockIdx.x;
  // balanced work mapping (bijective on 0..31): sgrp 0..3 -> {y0, 15-y0, 16+y0, 31-y0}
  const int yl = (int)blockIdx.y;
  const int sgrp = yl >> 3, y0 = yl & 7;
  const int yp = ((sgrp >> 1) << 4) + ((sgrp & 1) ? (15 - y0) : y0);
  const int rt = 31 - yp;                   // q row-tile (64 rows); ntiles = rt+1
  const int qh = wv >> 1;                   // q-half: 32 rows
  const int kh = wv & 1;                    // kpos-half: 32 positions per tile
  const int m0 = rt * 64 + qh * 32;         // wave's first q row
  const int swl = l15 & 7;

  // hoisted K/V staging source pointers (advance after each staged tile)
  const short* kPtr[2];
  const short* vPtr[2];
  int ldsOff[2];
#pragma unroll
  for (int i = 0; i < 2; ++i) {
    int slot = i * 256 + tid;                 // 0..511
    int r = slot >> 3;
    int c = ((slot & 7) ^ (r & 7)) << 3;
    kPtr[i] = kg + (bh * SEQ + r) * HDIM + c;
    vPtr[i] = vT + (bh * HDIM + r) * SEQ + c;
    ldsOff[i] = (i * 256 + wv * 64) * 8;
  }
#define STAGE_KV(KsB, VsB)                              \
  do {                                                  \
    _Pragma("unroll")                                   \
    for (int i = 0; i < 2; ++i) {                       \
      GL2LDS(kPtr[i], (KsB) + ldsOff[i]);               \
      GL2LDS(vPtr[i], (VsB) + ldsOff[i]);               \
      kPtr[i] += 64 * HDIM;                             \
      vPtr[i] += 64;                                    \
    }                                                   \
  } while (0)

  // Q frags (persistent): B-operand for S^T: n=q=m0+g*16+l15, k=d=kk*32+quad*8+j
  short8 aq[2][2];
#pragma unroll
  for (int g = 0; g < 2; g++) {
    const short* qp = qg + (long)(bh * SEQ + m0 + g * 16 + l15) * HDIM + quad * 8;
    aq[g][0] = *(const short8*)qp;
    aq[g][1] = *(const short8*)(qp + 32);
  }

  const short ONE = (short)0x3F80;  // bf16 1.0
  const short4v ones4 = {ONE, ONE, ONE, ONE};

  floatx4 o[2][4], lsum[2];
#pragma unroll
  for (int g = 0; g < 2; g++) {
    lsum[g] = (floatx4){0.f, 0.f, 0.f, 0.f};
#pragma unroll
    for (int nt = 0; nt < 4; nt++) o[g][nt] = (floatx4){0.f, 0.f, 0.f, 0.f};
  }

  const int ntiles = rt + 1;
  STAGE_KV(Ks[0], Vs[0]);

  for (int kt = 0; kt < ntiles; ++kt) {
    __syncthreads();                         // drains GL2LDS (vmcnt 0) + syncs: buf[kt&1] ready
    const int buf = kt & 1;
    if (kt + 1 < ntiles)                     // prefetch next tile; drained at NEXT barrier
      STAGE_KV(Ks[buf ^ 1], Vs[buf ^ 1]);

    const short* KsB = Ks[buf];
    const short* VsB = Vs[buf];

    // ---- S^T quarter = K[kh-half] . Q[qh-half]^T (16x16x32) ----
    // D[row=kpos(quad*4+r) within sub][col=q(l15)]
    floatx4 sc[2][2];                        // [g][sub]
#pragma unroll
    for (int g = 0; g < 2; g++)
#pragma unroll
      for (int sub = 0; sub < 2; sub++) sc[g][sub] = (floatx4){0.f, 0.f, 0.f, 0.f};
    __builtin_amdgcn_s_setprio(1);
#pragma unroll
    for (int sub = 0; sub < 2; sub++) {
      const short* kp = KsB + (kh * 32 + sub * 16 + l15) * 64;
      short8 kf0 = *(const short8*)(kp + ((quad ^ swl) << 3));         // A: m=kpos, k=d 0..31
      short8 kf1 = *(const short8*)(kp + (((4 + quad) ^ swl) << 3));   // k=d 32..63
#pragma unroll
      for (int g = 0; g < 2; g++) {
        sc[g][sub] = __builtin_amdgcn_mfma_f32_16x16x32_bf16(kf0, aq[g][0], sc[g][sub], 0, 0, 0);
        sc[g][sub] = __builtin_amdgcn_mfma_f32_16x16x32_bf16(kf1, aq[g][1], sc[g][sub], 0, 0, 0);
      }
    }
    __builtin_amdgcn_s_setprio(0);

    // ---- softmax (static max, exp2 domain) + pack P into K=16 A-frags (registers) ----
    short4v pa[2][2];
#pragma unroll
    for (int g = 0; g < 2; g++) {
      const int qrow = m0 + g * 16 + l15;
#pragma unroll
      for (int sub = 0; sub < 2; sub++) {
        const int kbase = kt * 64 + kh * 32 + sub * 16;
        const bool full = (kbase + 15) <= (m0 + g * 16);  // wave-uniform per (g,sub)
        unsigned u[4];
#pragma unroll
        for (int r = 0; r < 4; r++) {
          float pe = __builtin_amdgcn_exp2f(sc[g][sub][r]);
          if (!full) {
            const int kpos = kbase + quad * 4 + r;
            pe = (kpos <= qrow) ? pe : 0.f;
          }
          u[r] = __builtin_bit_cast(unsigned, pe);
        }
        uint2 w;
        // bf16-pair pack: select hi bytes of (u[r], u[r+1]) -> implicit trunc to bf16
        w.x = __builtin_amdgcn_perm(u[1], u[0], 0x07060302);   // k = quad*4 + {0,1}
        w.y = __builtin_amdgcn_perm(u[3], u[2], 0x07060302);   // k = quad*4 + {2,3}
        pa[g][sub] = __builtin_bit_cast(short4v, w);
      }
    }

    // ---- partial P @ V and P @ ones via 16x16x16 MFMA (k-dim = wave's kpos-half) ----
    __builtin_amdgcn_s_setprio(1);
#pragma unroll
    for (int sub = 0; sub < 2; sub++) {
      short4v bv[4];
#pragma unroll
      for (int nt = 0; nt < 4; nt++) {
        const int ch = (kh * 4 + sub * 2 + (quad >> 1)) ^ swl;   // 16B-chunk swizzle
        bv[nt] = *(const short4v*)(VsB + (nt * 16 + l15) * 64 + (ch << 3) + ((quad & 1) << 2));
      }
#pragma unroll
      for (int g = 0; g < 2; g++) {
        lsum[g] = __builtin_amdgcn_mfma_f32_16x16x16bf16_1k(pa[g][sub], ones4, lsum[g], 0, 0, 0);
#pragma unroll
        for (int nt = 0; nt < 4; nt++)
          o[g][nt] = __builtin_amdgcn_mfma_f32_16x16x16bf16_1k(pa[g][sub], bv[nt], o[g][nt], 0, 0, 0);
      }
    }
    __builtin_amdgcn_s_setprio(0);
  }
#undef STAGE_KV

  // ---- merge kpos-half partials: kh=1 writes to LDS scratch, kh=0 adds ----
  // FIELD-MAJOR layout [field][thr]: thr = qh*64+lane is contiguous -> conflict-free.
  __syncthreads();                         // all compute done; Ks/Vs reusable as scratch
  float* redO = (float*)&Ks[0][0];         // [32 fields][128 thr] = 16KB
  float* redL = (float*)&Vs[0][0];         // [8 fields][128 thr]  = 4KB
  const int thr = qh * 64 + lane;
  if (kh == 1) {
#pragma unroll
    for (int g = 0; g < 2; g++) {
#pragma unroll
      for (int nt = 0; nt < 4; nt++)
#pragma unroll
        for (int r = 0; r < 4; r++)
          redO[(g * 16 + nt * 4 + r) * 128 + thr] = o[g][nt][r];
#pragma unroll
      for (int r = 0; r < 4; r++) redL[(g * 4 + r) * 128 + thr] = lsum[g][r];
    }
  }
  __syncthreads();
  if (kh == 0) {
    const int b = bh >> 4, h = bh & 15;
#pragma unroll
    for (int g = 0; g < 2; g++) {
      floatx4 lt = lsum[g];
#pragma unroll
      for (int r = 0; r < 4; r++) lt[r] += redL[(g * 4 + r) * 128 + thr];
#pragma unroll
      for (int r = 0; r < 4; r++) {
        const float inv = 1.0f / lt[r];
        const int srow = m0 + g * 16 + quad * 4 + r;
#pragma unroll
        for (int nt = 0; nt < 4; nt++) {
          float val = o[g][nt][r] + redO[(g * 16 + nt * 4 + r) * 128 + thr];
          attn[(long)(b * SEQ + srow) * HIDDEN + h * HDIM + nt * 16 + l15] = f2bf(val * inv);
        }
      }
    }
  }
}

extern "C" void kernel_launch(void* const* d_in, const int* in_sizes, int n_in,
                              void* d_out, int out_size, void* d_ws, size_t ws_size,
                              hipStream_t stream) {
  const float* x     = (const float*)d_in[0];  // [2,2048,1024]
  const float* qkv_w = (const float*)d_in[1];  // [3072,1024]
  const float* out_w = (const float*)d_in[2];  // [1024,1024]
  float* out = (float*)d_out;                  // [2,2048,1024] fp32

  short* xb   = (short*)d_ws;                       // 4096*1024
  short* wqb  = xb  + MTOT * HIDDEN;                // 3072*1024
  short* wob  = wqb + 3 * HIDDEN * HIDDEN;          // 1024*1024
  short* qB   = wob + HIDDEN * HIDDEN;              // 32*2048*64
  short* kB   = qB  + BHN * SEQ * HDIM;
  short* vTB  = kB  + BHN * SEQ * HDIM;
  short* attn = vTB + BHN * SEQ * HDIM;             // 4096*1024

  // fused bf16 casts: (4096+3072+1024)*1024/4 = 2097152 vec4 -> 8192 blocks
  cvt3_f32_bf16<<<dim3(8192), dim3(256), 0, stream>>>(x, qkv_w, out_w, xb, wqb, wob);

  // QKV projection: M=4096, N=3072, K=1024, BK=64 (proven 128x128 structure + hoist + T1)
  gemm_bt<1, 128><<<dim3(3 * HIDDEN / 128, MTOT / 128), dim3(256), 0, stream>>>(
      xb, wqb, MTOT, 3 * HIDDEN, HIDDEN, nullptr, qB, kB, vTB);

  // causal attention: 64-row blocks, 2x2 (q-half x kpos-half) wave split, v10
  flash_attn<<<dim3(BHN, SEQ / 64), dim3(256), 0, stream>>>(qB, kB, vTB, attn);

  // output projection: M=4096, N=1024, K=1024 (128x64 tiles -> 512 blocks), BK=64
  gemm_bt<2, 64><<<dim3(HIDDEN / 64, MTOT / 128), dim3(256), 0, stream>>>(
      attn, wob, MTOT, HIDDEN, HIDDEN, out, nullptr, nullptr, nullptr);
}

// Round 10
// 168.716 us; speedup vs baseline: 1.3250x; 1.0086x over previous
//
#include <hip/hip_runtime.h>
#include <hip/hip_bf16.h>
#include <math.h>

// Problem constants (CPUEfficientCausalAttention): B=2, S=2048, HIDDEN=1024, H=16, hd=64
#define HIDDEN 1024
#define HEADS 16
#define HDIM 64
#define BATCH 2
#define SEQ 2048
#define BHN (BATCH*HEADS)   // 32
#define MTOT (BATCH*SEQ)    // 4096

typedef __attribute__((ext_vector_type(8))) short short8;   // 8 bf16 (16x16x32 A/B frag)
typedef __attribute__((ext_vector_type(4))) short short4v;  // 4 bf16 (16x16x16 A/B frag)
typedef __attribute__((ext_vector_type(4))) float floatx4;  // MFMA C/D frag

// global -> LDS direct (16B per lane; LDS dst is wave-uniform base, +lane*16 implicit)
#define GL2LDS(gsrc, ldst) __builtin_amdgcn_global_load_lds( \
    (const __attribute__((address_space(1))) void*)(gsrc), \
    (__attribute__((address_space(3))) void*)(ldst), 16, 0, 0)

__device__ __forceinline__ short f2bf(float f) {
  union { float f; unsigned u; } v; v.f = f;
  unsigned u = v.u;
  unsigned r = (u + 0x7fffu + ((u >> 16) & 1u)) >> 16;  // RNE
  return (short)r;
}

// One fused fp32->bf16 cast for x (1048576 vec4), qkv_w (786432), out_w (262144)
__global__ __launch_bounds__(256) void cvt3_f32_bf16(
    const float* __restrict__ a, const float* __restrict__ b, const float* __restrict__ c,
    short* __restrict__ oa, short* __restrict__ ob, short* __restrict__ oc) {
  int i = blockIdx.x * 256 + threadIdx.x;
  const float* src; short* dst; int j;
  if (i < 1048576)      { src = a; dst = oa; j = i; }
  else if (i < 1835008) { src = b; dst = ob; j = i - 1048576; }
  else                  { src = c; dst = oc; j = i - 1835008; }
  float4 f = reinterpret_cast<const float4*>(src)[j];
  short4 o;
  o.x = f2bf(f.x); o.y = f2bf(f.y); o.z = f2bf(f.z); o.w = f2bf(f.w);
  reinterpret_cast<short4*>(dst)[j] = o;
}

// C[M,N] = A[M,K] @ B[N,K]^T, bf16 in, fp32 accum.  (round-7 structure + BM param)
// BMxBN tile, BK=64 (XOR-swizzled LDS rows of 128B keep b128 reads bank-minimal),
// 4 waves in 2x2, each wave (BM/2)x(BN/2). Hoisted staging pointers + T1 XCD swizzle.
// BM=64 for the output projection: 1024 blocks = 4/CU (512 blocks @BM=128 was
// 2/CU grid-limited residency -- the same latency disease flash had in R0).
// EPI==1 (BM=128,BN=128): scatter qkv epilogue (q scaled by hd^-0.5*log2e, k row-major,
//                         v transposed)
// EPI==2: plain fp32 C row-major
template<int EPI, int BM, int BN>
__global__ __launch_bounds__(256) void gemm_bt(
    const short* __restrict__ A, const short* __restrict__ B,
    int M, int N, int K,
    float* __restrict__ outF,
    short* __restrict__ outQ, short* __restrict__ outK, short* __restrict__ outV)
{
  constexpr int WM = BM / 2;    // wave row extent
  constexpr int WN = BN / 2;    // wave col extent
  constexpr int MI = BM / 32;   // 16-row tiles per wave
  constexpr int NI = BN / 32;   // 16-col tiles per wave
  constexpr int ARD = BM / 32;  // A staging loads per thread
  constexpr int BRD = BN / 32;  // B staging loads per thread
  __shared__ __align__(16) short As[BM*64];
  __shared__ __align__(16) short Bs[BN*64];
  const int tid = threadIdx.x;
  const int wv = tid >> 6;
  const int lane = tid & 63;
  const int l15 = lane & 15;
  const int quad = lane >> 4;
  const int swl = l15 & 7;
  const int wm = wv >> 1, wn = wv & 1;

  // T1 XCD swizzle (bijective since nwg % 8 == 0)
  const int nwg = gridDim.x * gridDim.y;
  const int cpx = nwg >> 3;
  int wg = (int)blockIdx.y * gridDim.x + blockIdx.x;
  wg = (wg & 7) * cpx + (wg >> 3);
  const int bx = wg % gridDim.x, by = wg / gridDim.x;
  const int row0 = by * BM, col0 = bx * BN;

  const int nsteps = K >> 6;

  // hoisted per-lane staging source pointers (advance by 64 shorts per K-step)
  const short* aSrc[ARD];
#pragma unroll
  for (int rd = 0; rd < ARD; ++rd) {
    int chunk = rd * 256 + tid;
    int r = chunk >> 3, c = ((chunk & 7) ^ (r & 7)) << 3;
    aSrc[rd] = A + (long)(row0 + r) * K + c;
  }
  const short* bSrc[BRD];
#pragma unroll
  for (int rd = 0; rd < BRD; ++rd) {
    int chunk = rd * 256 + tid;
    int r = chunk >> 3, c = ((chunk & 7) ^ (r & 7)) << 3;
    bSrc[rd] = B + (long)(col0 + r) * K + c;
  }

  floatx4 acc[MI][NI];
#pragma unroll
  for (int i = 0; i < MI; i++)
#pragma unroll
    for (int j = 0; j < NI; j++) acc[i][j] = (floatx4){0.f, 0.f, 0.f, 0.f};

  for (int t = 0; t < nsteps; ++t) {
    // stage A [BM][64] and B [BN][64], XOR-swizzled on source col
#pragma unroll
    for (int rd = 0; rd < ARD; ++rd) {
      GL2LDS(aSrc[rd], As + (rd * 256 + wv * 64) * 8);
      aSrc[rd] += 64;
    }
#pragma unroll
    for (int rd = 0; rd < BRD; ++rd) {
      GL2LDS(bSrc[rd], Bs + (rd * 256 + wv * 64) * 8);
      bSrc[rd] += 64;
    }
    __syncthreads();

    short8 af[MI][2], bfr[NI][2];
#pragma unroll
    for (int mi = 0; mi < MI; mi++) {
      const short* ap = As + (wm * WM + mi * 16 + l15) * 64;
#pragma unroll
      for (int kk = 0; kk < 2; kk++)
        af[mi][kk] = *(const short8*)(ap + (((kk * 4 + quad) ^ swl) << 3));
    }
#pragma unroll
    for (int ni = 0; ni < NI; ni++) {
      const short* bp = Bs + (wn * WN + ni * 16 + l15) * 64;
#pragma unroll
      for (int kk = 0; kk < 2; kk++)
        bfr[ni][kk] = *(const short8*)(bp + (((kk * 4 + quad) ^ swl) << 3));
    }
    __builtin_amdgcn_s_setprio(1);
#pragma unroll
    for (int mi = 0; mi < MI; mi++)
#pragma unroll
      for (int ni = 0; ni < NI; ni++)
#pragma unroll
        for (int kk = 0; kk < 2; kk++)
          acc[mi][ni] = __builtin_amdgcn_mfma_f32_16x16x32_bf16(af[mi][kk], bfr[ni][kk], acc[mi][ni], 0, 0, 0);
    __builtin_amdgcn_s_setprio(0);
    __syncthreads();
  }

  if (EPI == 2) {
#pragma unroll
    for (int mi = 0; mi < MI; mi++) {
      int rr = row0 + wm * WM + mi * 16 + quad * 4;
#pragma unroll
      for (int ni = 0; ni < NI; ni++) {
        int cc = col0 + wn * WN + ni * 16 + l15;
#pragma unroll
        for (int r = 0; r < 4; r++)
          outF[(long)(rr + r) * N + cc] = acc[mi][ni][r];
      }
    }
  } else {
    // qkv scatter: j = t*1024 + h*64 + d ; i = b*2048 + s
#pragma unroll
    for (int mi = 0; mi < MI; mi++) {
      int rowg = row0 + wm * WM + mi * 16 + quad * 4;
#pragma unroll
      for (int ni = 0; ni < NI; ni++) {
        int j = col0 + wn * WN + ni * 16 + l15;
        int t = j >> 10;
        int rem = j & 1023;
        int h = rem >> 6, d = rem & 63;
#pragma unroll
        for (int r = 0; r < 4; r++) {
          int i = rowg + r;
          int b = i >> 11, s = i & 2047;
          int bh = b * HEADS + h;
          float v = acc[mi][ni][r];
          // q scale = hd^-0.5 * log2(e) so flash can use raw v_exp_f32 (2^x)
          if (t == 0)      outQ[(bh * SEQ + s) * HDIM + d] = f2bf(v * 0.18033688011112042f);
          else if (t == 1) outK[(bh * SEQ + s) * HDIM + d] = f2bf(v);
          else             outV[(bh * HDIM + d) * SEQ + s] = f2bf(v);          // transposed
        }
      }
    }
  }
}

// Flash attention v10 (PROVEN, round-7/9): v9 structure (2x2 q-half x kpos-half wave
// split, additive static-max partials, LDS merge) + three issue-rate fixes:
//  1. merge scratch FIELD-MAJOR [field][thr] -> conflict-free.
//  2. staging source pointers hoisted (computed once, advanced per tile).
//  3. P-pack via v_perm_b32 (1 inst/pair, implicit bf16 trunc).
// NOTE (round-8 lesson): the GL2LDS->LDS->next-barrier pipeline IS the latency hider
// (prefetch distance 1: barrier drains loads one full compute-phase old). Replacing
// it with direct per-tile L2 loads exposed ~200cyc/tile -> 2.3x regression. Keep.
__global__ __launch_bounds__(256, 4) void flash_attn(
    const short* __restrict__ qg, const short* __restrict__ kg,
    const short* __restrict__ vT, short* __restrict__ attn)
{
  __shared__ __align__(16) short Ks[2][64 * 64];
  __shared__ __align__(16) short Vs[2][64 * 64];

  const int tid = threadIdx.x;
  const int wv = tid >> 6, lane = tid & 63;
  const int l15 = lane & 15, quad = lane >> 4;
  const int bh = blockIdx.x;
  // balanced work mapping (bijective on 0..31): sgrp 0..3 -> {y0, 15-y0, 16+y0, 31-y0}
  const int yl = (int)blockIdx.y;
  const int sgrp = yl >> 3, y0 = yl & 7;
  const int yp = ((sgrp >> 1) << 4) + ((sgrp & 1) ? (15 - y0) : y0);
  const int rt = 31 - yp;                   // q row-tile (64 rows); ntiles = rt+1
  const int qh = wv >> 1;                   // q-half: 32 rows
  const int kh = wv & 1;                    // kpos-half: 32 positions per tile
  const int m0 = rt * 64 + qh * 32;         // wave's first q row
  const int swl = l15 & 7;

  // hoisted K/V staging source pointers (advance after each staged tile)
  const short* kPtr[2];
  const short* vPtr[2];
  int ldsOff[2];
#pragma unroll
  for (int i = 0; i < 2; ++i) {
    int slot = i * 256 + tid;                 // 0..511
    int r = slot >> 3;
    int c = ((slot & 7) ^ (r & 7)) << 3;
    kPtr[i] = kg + (bh * SEQ + r) * HDIM + c;
    vPtr[i] = vT + (bh * HDIM + r) * SEQ + c;
    ldsOff[i] = (i * 256 + wv * 64) * 8;
  }
#define STAGE_KV(KsB, VsB)                              \
  do {                                                  \
    _Pragma("unroll")                                   \
    for (int i = 0; i < 2; ++i) {                       \
      GL2LDS(kPtr[i], (KsB) + ldsOff[i]);               \
      GL2LDS(vPtr[i], (VsB) + ldsOff[i]);               \
      kPtr[i] += 64 * HDIM;                             \
      vPtr[i] += 64;                                    \
    }                                                   \
  } while (0)

  // Q frags (persistent): B-operand for S^T: n=q=m0+g*16+l15, k=d=kk*32+quad*8+j
  short8 aq[2][2];
#pragma unroll
  for (int g = 0; g < 2; g++) {
    const short* qp = qg + (long)(bh * SEQ + m0 + g * 16 + l15) * HDIM + quad * 8;
    aq[g][0] = *(const short8*)qp;
    aq[g][1] = *(const short8*)(qp + 32);
  }

  const short ONE = (short)0x3F80;  // bf16 1.0
  const short4v ones4 = {ONE, ONE, ONE, ONE};

  floatx4 o[2][4], lsum[2];
#pragma unroll
  for (int g = 0; g < 2; g++) {
    lsum[g] = (floatx4){0.f, 0.f, 0.f, 0.f};
#pragma unroll
    for (int nt = 0; nt < 4; nt++) o[g][nt] = (floatx4){0.f, 0.f, 0.f, 0.f};
  }

  const int ntiles = rt + 1;
  STAGE_KV(Ks[0], Vs[0]);

  for (int kt = 0; kt < ntiles; ++kt) {
    __syncthreads();                         // drains GL2LDS (vmcnt 0) + syncs: buf[kt&1] ready
    const int buf = kt & 1;
    if (kt + 1 < ntiles)                     // prefetch next tile; drained at NEXT barrier
      STAGE_KV(Ks[buf ^ 1], Vs[buf ^ 1]);

    const short* KsB = Ks[buf];
    const short* VsB = Vs[buf];

    // ---- S^T quarter = K[kh-half] . Q[qh-half]^T (16x16x32) ----
    // D[row=kpos(quad*4+r) within sub][col=q(l15)]
    floatx4 sc[2][2];                        // [g][sub]
#pragma unroll
    for (int g = 0; g < 2; g++)
#pragma unroll
      for (int sub = 0; sub < 2; sub++) sc[g][sub] = (floatx4){0.f, 0.f, 0.f, 0.f};
    __builtin_amdgcn_s_setprio(1);
#pragma unroll
    for (int sub = 0; sub < 2; sub++) {
      const short* kp = KsB + (kh * 32 + sub * 16 + l15) * 64;
      short8 kf0 = *(const short8*)(kp + ((quad ^ swl) << 3));         // A: m=kpos, k=d 0..31
      short8 kf1 = *(const short8*)(kp + (((4 + quad) ^ swl) << 3));   // k=d 32..63
#pragma unroll
      for (int g = 0; g < 2; g++) {
        sc[g][sub] = __builtin_amdgcn_mfma_f32_16x16x32_bf16(kf0, aq[g][0], sc[g][sub], 0, 0, 0);
        sc[g][sub] = __builtin_amdgcn_mfma_f32_16x16x32_bf16(kf1, aq[g][1], sc[g][sub], 0, 0, 0);
      }
    }
    __builtin_amdgcn_s_setprio(0);

    // ---- softmax (static max, exp2 domain) + pack P into K=16 A-frags (registers) ----
    short4v pa[2][2];
#pragma unroll
    for (int g = 0; g < 2; g++) {
      const int qrow = m0 + g * 16 + l15;
#pragma unroll
      for (int sub = 0; sub < 2; sub++) {
        const int kbase = kt * 64 + kh * 32 + sub * 16;
        const bool full = (kbase + 15) <= (m0 + g * 16);  // wave-uniform per (g,sub)
        unsigned u[4];
#pragma unroll
        for (int r = 0; r < 4; r++) {
          float pe = __builtin_amdgcn_exp2f(sc[g][sub][r]);
          if (!full) {
            const int kpos = kbase + quad * 4 + r;
            pe = (kpos <= qrow) ? pe : 0.f;
          }
          u[r] = __builtin_bit_cast(unsigned, pe);
        }
        uint2 w;
        // bf16-pair pack: select hi bytes of (u[r], u[r+1]) -> implicit trunc to bf16
        w.x = __builtin_amdgcn_perm(u[1], u[0], 0x07060302);   // k = quad*4 + {0,1}
        w.y = __builtin_amdgcn_perm(u[3], u[2], 0x07060302);   // k = quad*4 + {2,3}
        pa[g][sub] = __builtin_bit_cast(short4v, w);
      }
    }

    // ---- partial P @ V and P @ ones via 16x16x16 MFMA (k-dim = wave's kpos-half) ----
    __builtin_amdgcn_s_setprio(1);
#pragma unroll
    for (int sub = 0; sub < 2; sub++) {
      short4v bv[4];
#pragma unroll
      for (int nt = 0; nt < 4; nt++) {
        const int ch = (kh * 4 + sub * 2 + (quad >> 1)) ^ swl;   // 16B-chunk swizzle
        bv[nt] = *(const short4v*)(VsB + (nt * 16 + l15) * 64 + (ch << 3) + ((quad & 1) << 2));
      }
#pragma unroll
      for (int g = 0; g < 2; g++) {
        lsum[g] = __builtin_amdgcn_mfma_f32_16x16x16bf16_1k(pa[g][sub], ones4, lsum[g], 0, 0, 0);
#pragma unroll
        for (int nt = 0; nt < 4; nt++)
          o[g][nt] = __builtin_amdgcn_mfma_f32_16x16x16bf16_1k(pa[g][sub], bv[nt], o[g][nt], 0, 0, 0);
      }
    }
    __builtin_amdgcn_s_setprio(0);
  }
#undef STAGE_KV

  // ---- merge kpos-half partials: kh=1 writes to LDS scratch, kh=0 adds ----
  // FIELD-MAJOR layout [field][thr]: thr = qh*64+lane is contiguous -> conflict-free.
  __syncthreads();                         // all compute done; Ks/Vs reusable as scratch
  float* redO = (float*)&Ks[0][0];         // [32 fields][128 thr] = 16KB
  float* redL = (float*)&Vs[0][0];         // [8 fields][128 thr]  = 4KB
  const int thr = qh * 64 + lane;
  if (kh == 1) {
#pragma unroll
    for (int g = 0; g < 2; g++) {
#pragma unroll
      for (int nt = 0; nt < 4; nt++)
#pragma unroll
        for (int r = 0; r < 4; r++)
          redO[(g * 16 + nt * 4 + r) * 128 + thr] = o[g][nt][r];
#pragma unroll
      for (int r = 0; r < 4; r++) redL[(g * 4 + r) * 128 + thr] = lsum[g][r];
    }
  }
  __syncthreads();
  if (kh == 0) {
    const int b = bh >> 4, h = bh & 15;
#pragma unroll
    for (int g = 0; g < 2; g++) {
      floatx4 lt = lsum[g];
#pragma unroll
      for (int r = 0; r < 4; r++) lt[r] += redL[(g * 4 + r) * 128 + thr];
#pragma unroll
      for (int r = 0; r < 4; r++) {
        const float inv = 1.0f / lt[r];
        const int srow = m0 + g * 16 + quad * 4 + r;
#pragma unroll
        for (int nt = 0; nt < 4; nt++) {
          float val = o[g][nt][r] + redO[(g * 16 + nt * 4 + r) * 128 + thr];
          attn[(long)(b * SEQ + srow) * HIDDEN + h * HDIM + nt * 16 + l15] = f2bf(val * inv);
        }
      }
    }
  }
}

extern "C" void kernel_launch(void* const* d_in, const int* in_sizes, int n_in,
                              void* d_out, int out_size, void* d_ws, size_t ws_size,
                              hipStream_t stream) {
  const float* x     = (const float*)d_in[0];  // [2,2048,1024]
  const float* qkv_w = (const float*)d_in[1];  // [3072,1024]
  const float* out_w = (const float*)d_in[2];  // [1024,1024]
  float* out = (float*)d_out;                  // [2,2048,1024] fp32

  short* xb   = (short*)d_ws;                       // 4096*1024
  short* wqb  = xb  + MTOT * HIDDEN;                // 3072*1024
  short* wob  = wqb + 3 * HIDDEN * HIDDEN;          // 1024*1024
  short* qB   = wob + HIDDEN * HIDDEN;              // 32*2048*64
  short* kB   = qB  + BHN * SEQ * HDIM;
  short* vTB  = kB  + BHN * SEQ * HDIM;
  short* attn = vTB + BHN * SEQ * HDIM;             // 4096*1024

  // fused bf16 casts: (4096+3072+1024)*1024/4 = 2097152 vec4 -> 8192 blocks
  cvt3_f32_bf16<<<dim3(8192), dim3(256), 0, stream>>>(x, qkv_w, out_w, xb, wqb, wob);

  // QKV projection: M=4096, N=3072, K=1024, BK=64 (proven 128x128 structure + hoist + T1)
  gemm_bt<1, 128, 128><<<dim3(3 * HIDDEN / 128, MTOT / 128), dim3(256), 0, stream>>>(
      xb, wqb, MTOT, 3 * HIDDEN, HIDDEN, nullptr, qB, kB, vTB);

  // causal attention: 64-row blocks, 2x2 (q-half x kpos-half) wave split, v10
  flash_attn<<<dim3(BHN, SEQ / 64), dim3(256), 0, stream>>>(qB, kB, vTB, attn);

  // output projection: M=4096, N=1024, K=1024 — 64x64 tiles -> 1024 blocks (4/CU,
  // was 512 @128x64 = 2/CU grid-limited)
  gemm_bt<2, 64, 64><<<dim3(HIDDEN / 64, MTOT / 64), dim3(256), 0, stream>>>(
      attn, wob, MTOT, HIDDEN, HIDDEN, out, nullptr, nullptr, nullptr);
}